// Round 1
// 211.816 us; speedup vs baseline: 1.1021x; 1.1021x over previous
//
#include <hip/hip_runtime.h>

#define N_NODES  10000
#define N_EDGES  320000
#define N_GRAPHS 64

// prep kernel role partition
#define RB 1250   // repack+hist blocks (ceil(320000/256))
#define RP 313    // pq1 blocks (ceil(10000/32))
#define RW 256    // w2-split blocks (512*128/256)

typedef __attribute__((ext_vector_type(8))) __bf16 bf16x8;
typedef __attribute__((ext_vector_type(4))) float f32x4;
typedef __attribute__((ext_vector_type(4))) unsigned int u32x4;

__device__ __forceinline__ float sigm(float z) { return 1.0f / (1.0f + __expf(-z)); }

// round-to-nearest-even f32 -> bf16 bits
__device__ __forceinline__ unsigned short f2bf(float f) {
    unsigned int u = __float_as_uint(f);
    return (unsigned short)((u + 0x7fffu + ((u >> 16) & 1u)) >> 16);
}
__device__ __forceinline__ float bf2f(unsigned short h) { return __uint_as_float(((unsigned int)h) << 16); }
__device__ __forceinline__ float bflo(unsigned int u) { return __uint_as_float(u << 16); }
__device__ __forceinline__ float bfhi(unsigned int u) { return __uint_as_float(u & 0xffff0000u); }

// ---------------- fused prep: repack(+self-detect int width)+hist | pq1 | w2split | g-zero ----
// role by blockIdx.x. All roles independent.
__global__ __launch_bounds__(256) void prep_k(
        const unsigned int* __restrict__ ei_raw, const unsigned int* __restrict__ b_raw,
        const float* __restrict__ x, const float* __restrict__ W1, const float* __restrict__ b1,
        const float* __restrict__ W2,
        int* __restrict__ src, int* __restrict__ dst, int* __restrict__ bat,
        int* __restrict__ deg, float* __restrict__ P1, unsigned short* __restrict__ Q1,
        unsigned short* __restrict__ Bh, unsigned short* __restrict__ Bl,
        float* __restrict__ g) {
    int bx = blockIdx.x, t = threadIdx.x;
    if (bx < RB) {
        // ---- per-block int-width self-detection ----
        // Sample odd words of a 512-word window. int64 (values < 2^31) -> high words all 0.
        // int32 -> words are values, overwhelmingly nonzero (incl. sorted batch: >=50 nonzero).
        __shared__ int snz[2];
        if (t < 2) snz[t] = 0;
        __syncthreads();
        {
            unsigned int wv = ei_raw[bx * 512 + 2 * t + 1];   // bx<=1249 -> max word 639999, in range
            unsigned long long m = __ballot(wv != 0);
            if ((t & 63) == 0 && m) atomicAdd(&snz[0], __popcll(m));
        }
        if (bx * 256 < N_NODES) {
            int w0 = min(bx * 512, N_NODES - 512);            // stay inside int32 buffer (10000 words)
            unsigned int bv = b_raw[w0 + 2 * t + 1];
            unsigned long long m = __ballot(bv != 0);
            if ((t & 63) == 0 && m) atomicAdd(&snz[1], __popcll(m));
        }
        __syncthreads();
        int i = bx * 256 + t;
        int i32e = snz[0] > 16;
        const int* ei = (const int*)ei_raw;
        if (i < N_EDGES) {
            int s = i32e ? ei[i] : ei[2 * i];
            int d = i32e ? ei[N_EDGES + i] : ei[2 * (N_EDGES + i)];
            src[i] = s;
            dst[i] = d;
            atomicAdd(&deg[d], 1);
        }
        if (i < N_NODES) {
            int i32b = snz[1] > 16;
            const int* bb = (const int*)b_raw;
            bat[i] = i32b ? bb[i] : bb[2 * i];
        }
    } else if (bx < RB + RP) {
        // ---- pq1: P1[n][c] = x[n]·(W1[0:3]-W1[3:6])[c] + b1[c] ; Q1[n][c] = x[n]·W1[3:6][c] bf16
        __shared__ float xs[96];
        int c = t;  // 0..255
        float k0, k1, k2, bias;
        if (c < 128) {
            k0 = W1[0 * 128 + c] - W1[3 * 128 + c];
            k1 = W1[1 * 128 + c] - W1[4 * 128 + c];
            k2 = W1[2 * 128 + c] - W1[5 * 128 + c];
            bias = b1[c];
        } else {
            int cc = c - 128;
            k0 = W1[3 * 128 + cc];
            k1 = W1[4 * 128 + cc];
            k2 = W1[5 * 128 + cc];
            bias = 0.f;
        }
        int n0 = (bx - RB) * 32;
        int nmax = min(32, N_NODES - n0);
        if (t < 96) xs[t] = (t < nmax * 3) ? x[n0 * 3 + t] : 0.f;
        __syncthreads();
        for (int tt = 0; tt < nmax; tt++) {
            float v = bias + xs[tt * 3 + 0] * k0 + xs[tt * 3 + 1] * k1 + xs[tt * 3 + 2] * k2;
            if (c < 128) P1[(n0 + tt) * 128 + c] = v;
            else         Q1[(n0 + tt) * 128 + (c - 128)] = f2bf(v);
        }
    } else if (bx < RB + RP + RW) {
        // ---- W2 -> transposed split-bf16 B: Bh/Bl[n][k] = split(Wc[k][n]), n in [0,512), k in [0,128)
        int idx = (bx - RB - RP) * 256 + t;  // 0..65535
        int nn = idx >> 7, k = idx & 127;
        float wc;
        if (nn < 256) wc = W2[k * 256 + nn] - W2[(128 + k) * 256 + nn];
        else          wc = W2[(128 + k) * 256 + (nn - 256)];
        unsigned short h = f2bf(wc);
        Bh[idx] = h;
        Bl[idx] = f2bf(wc - bf2f(h));
    } else {
        // ---- zero g (64*256 floats) with one block
        float4 z = make_float4(0.f, 0.f, 0.f, 0.f);
#pragma unroll
        for (int it = 0; it < 16; it++) *(float4*)&g[(t + it * 256) * 4] = z;
    }
}

// ---------------- exclusive scan of degrees: shuffle-scan, 2 barriers ----------------
__global__ void scan_k(const int* __restrict__ deg, int* __restrict__ offs,
                       int* __restrict__ cursor, int n) {
    __shared__ int wsum[16];
    int t = threadIdx.x;  // 1024 threads x 10 elements
    int base = t * 10;
    int v[10];
    int run = 0;
#pragma unroll
    for (int k = 0; k < 10; k++) {
        int i = base + k;
        int d = (i < n) ? deg[i] : 0;
        v[k] = run;
        run += d;
    }
    int lane = t & 63;
    int incl = run;
#pragma unroll
    for (int d = 1; d < 64; d <<= 1) {
        int u = __shfl_up(incl, d);
        if (lane >= d) incl += u;
    }
    if (lane == 63) wsum[t >> 6] = incl;
    __syncthreads();
    if (t < 16) {
        int s = wsum[t];
#pragma unroll
        for (int d = 1; d < 16; d <<= 1) {
            int u = __shfl_up(s, d, 16);
            if (t >= d) s += u;
        }
        wsum[t] = s;  // inclusive wave sums
    }
    __syncthreads();
    int wbase = (t >> 6) ? wsum[(t >> 6) - 1] : 0;
    int excl = wbase + incl - run;
#pragma unroll
    for (int k = 0; k < 10; k++) {
        int i = base + k;
        if (i < n) { int o = excl + v[k]; offs[i] = o; cursor[i] = o; }
    }
    if (t == 1023) offs[n] = wsum[15];
}

__global__ void scatter_k(const int* __restrict__ src, const int* __restrict__ dst,
                          int* __restrict__ cursor, int* __restrict__ csr, int E) {
    int e = blockIdx.x * blockDim.x + threadIdx.x;
    if (e < E) {
        int pos = atomicAdd(&cursor[dst[e]], 1);
        csr[pos] = src[e];
    }
}

// ---------------- EdgeConv1: h1 = sigmoid(P1 + max_j Q1[j]) -> split bf16 (hi/lo) ----------------
__global__ void econv1_k(const float* __restrict__ P1, const unsigned int* __restrict__ Q1u,
                         const int* __restrict__ offs, const int* __restrict__ csr,
                         unsigned short* __restrict__ h1h, unsigned short* __restrict__ h1l) {
    int i = blockIdx.x;
    int c = threadIdx.x;  // 0..63 -> channels 2c, 2c+1
    int s = offs[i], e = offs[i + 1];
    float o0 = 0.f, o1 = 0.f;
    if (e > s) {
        float z0 = -3.4e38f, z1 = -3.4e38f;
        int k = s;
        for (; k + 3 < e; k += 4) {
            int j0 = csr[k], j1 = csr[k + 1], j2 = csr[k + 2], j3 = csr[k + 3];
            unsigned int u0 = Q1u[j0 * 64 + c];
            unsigned int u1 = Q1u[j1 * 64 + c];
            unsigned int u2 = Q1u[j2 * 64 + c];
            unsigned int u3 = Q1u[j3 * 64 + c];
            z0 = fmaxf(z0, fmaxf(fmaxf(bflo(u0), bflo(u1)), fmaxf(bflo(u2), bflo(u3))));
            z1 = fmaxf(z1, fmaxf(fmaxf(bfhi(u0), bfhi(u1)), fmaxf(bfhi(u2), bfhi(u3))));
        }
        for (; k < e; k++) {
            unsigned int u = Q1u[csr[k] * 64 + c];
            z0 = fmaxf(z0, bflo(u));
            z1 = fmaxf(z1, bfhi(u));
        }
        unsigned long long pv =
            __builtin_nontemporal_load((const unsigned long long*)&P1[i * 128 + 2 * c]);
        float px = __uint_as_float((unsigned int)pv);
        float py = __uint_as_float((unsigned int)(pv >> 32));
        o0 = sigm(px + z0);
        o1 = sigm(py + z1);
    }
    unsigned short hh0 = f2bf(o0), hh1 = f2bf(o1);
    unsigned short hl0 = f2bf(o0 - bf2f(hh0)), hl1 = f2bf(o1 - bf2f(hh1));
    *(ushort2*)&h1h[i * 128 + 2 * c] = make_ushort2(hh0, hh1);
    *(ushort2*)&h1l[i * 128 + 2 * c] = make_ushort2(hl0, hl1);
}

// ---------------- GEMM2 via split-bf16 MFMA: [10000,128] @ [128,512] ----------------
// C = Ah*Bh + Al*Bh + Ah*Bl  (3x mfma_f32_16x16x32_bf16), error ~2^-18 rel.
// Block: 64x64 tile, 4 waves (16 rows each). LDS tiles stored [row][k] with
// XOR swizzle byte^=((row&7)<<4) so stride-256B fragment reads are 2-way (free).
__global__ __launch_bounds__(256) void gemm2_k(
        const unsigned short* __restrict__ Ahg, const unsigned short* __restrict__ Alg,
        const unsigned short* __restrict__ Bhg, const unsigned short* __restrict__ Blg,
        const float* __restrict__ b2, float* __restrict__ P2,
        unsigned short* __restrict__ Q2, int n) {
    __shared__ __align__(16) char smem[65536];
    char* Ahb = smem;
    char* Alb = smem + 16384;
    char* Bhb = smem + 32768;
    char* Blb = smem + 49152;
    int t = threadIdx.x;
    int m0 = blockIdx.x * 64;
    int n0 = blockIdx.y * 64;
    // stage: each array is 64 rows x 128 bf16 = 1024 chunks of 16B; 4 chunks/thread/array
#pragma unroll
    for (int it = 0; it < 4; it++) {
        int c = t + it * 256;
        int row = c >> 4, kb = c & 15;
        int dsa = (row * 256 + kb * 16) ^ ((row & 7) << 4);
        u32x4 va = {0u, 0u, 0u, 0u}, vl = {0u, 0u, 0u, 0u};
        if (m0 + row < n) {
            va = *(const u32x4*)&Ahg[(m0 + row) * 128 + kb * 8];
            vl = *(const u32x4*)&Alg[(m0 + row) * 128 + kb * 8];
        }
        *(u32x4*)(Ahb + dsa) = va;
        *(u32x4*)(Alb + dsa) = vl;
        *(u32x4*)(Bhb + dsa) = *(const u32x4*)&Bhg[(n0 + row) * 128 + kb * 8];
        *(u32x4*)(Blb + dsa) = *(const u32x4*)&Blg[(n0 + row) * 128 + kb * 8];
    }
    __syncthreads();

    int w = t >> 6, lane = t & 63;
    int lr = lane & 15, lg = lane >> 4;
    // A fragments: lane holds A[m=16w+lr][k = kk*32 + lg*8 + e]
    int am = 16 * w + lr;
    int abase = am * 256 + lg * 16;
    int asw = (am & 7) << 4;
    bf16x8 ah[4], al[4];
#pragma unroll
    for (int kk = 0; kk < 4; kk++) {
        int off = (abase + kk * 64) ^ asw;
        ah[kk] = *(const bf16x8*)(Ahb + off);
        al[kk] = *(const bf16x8*)(Alb + off);
    }
    int bsw = (lr & 7) << 4;  // (n_l & 7) == (lr & 7) for every n-tile
#pragma unroll
    for (int nt = 0; nt < 4; nt++) {
        int nb = (nt * 16 + lr) * 256 + lg * 16;
        f32x4 acc = {0.f, 0.f, 0.f, 0.f};
#pragma unroll
        for (int kk = 0; kk < 4; kk++) {
            int off = (nb + kk * 64) ^ bsw;
            bf16x8 bh = *(const bf16x8*)(Bhb + off);
            bf16x8 bl = *(const bf16x8*)(Blb + off);
            acc = __builtin_amdgcn_mfma_f32_16x16x32_bf16(ah[kk], bh, acc, 0, 0, 0);
            acc = __builtin_amdgcn_mfma_f32_16x16x32_bf16(al[kk], bh, acc, 0, 0, 0);
            acc = __builtin_amdgcn_mfma_f32_16x16x32_bf16(ah[kk], bl, acc, 0, 0, 0);
        }
        // D layout: col = lane&15, row = 4*(lane>>4) + r
        int colg = n0 + nt * 16 + lr;
        int mbase = m0 + 16 * w + 4 * lg;
        if (colg < 256) {
            float bias = b2[colg];
#pragma unroll
            for (int r = 0; r < 4; r++) {
                int m = mbase + r;
                if (m < n)
                    __builtin_nontemporal_store(acc[r] + bias, &P2[(size_t)m * 256 + colg]);
            }
        } else {
            int qc = colg - 256;
#pragma unroll
            for (int r = 0; r < 4; r++) {
                int m = mbase + r;
                if (m < n) Q2[(size_t)m * 256 + qc] = f2bf(acc[r]);
            }
        }
    }
}

// ---------------- EdgeConv2 + fused graph max-pool, channel-split for L2 fit ----------------
// grid (N_NODES, 2): half = blockIdx.y selects 64 of the 128 uint-pairs -> 2.56MB hot set per half
__global__ void econv2_k(const float* __restrict__ P2, const unsigned int* __restrict__ Q2u,
                         const int* __restrict__ offs, const int* __restrict__ csr,
                         const int* __restrict__ bat, float* __restrict__ g) {
    int i = blockIdx.x;
    int s = offs[i], e = offs[i + 1];
    if (s == e) return;  // empty row -> h2 = 0, contributes nothing (g init 0)
    int cc = blockIdx.y * 64 + threadIdx.x;  // uint channel 0..127
    float z0 = -3.4e38f, z1 = -3.4e38f;
    int k = s;
    for (; k + 3 < e; k += 4) {
        int j0 = csr[k], j1 = csr[k + 1], j2 = csr[k + 2], j3 = csr[k + 3];
        unsigned int u0 = Q2u[(size_t)j0 * 128 + cc];
        unsigned int u1 = Q2u[(size_t)j1 * 128 + cc];
        unsigned int u2 = Q2u[(size_t)j2 * 128 + cc];
        unsigned int u3 = Q2u[(size_t)j3 * 128 + cc];
        z0 = fmaxf(z0, fmaxf(fmaxf(bflo(u0), bflo(u1)), fmaxf(bflo(u2), bflo(u3))));
        z1 = fmaxf(z1, fmaxf(fmaxf(bfhi(u0), bfhi(u1)), fmaxf(bfhi(u2), bfhi(u3))));
    }
    for (; k < e; k++) {
        unsigned int u = Q2u[(size_t)csr[k] * 128 + cc];
        z0 = fmaxf(z0, bflo(u));
        z1 = fmaxf(z1, bfhi(u));
    }
    unsigned long long pv =
        __builtin_nontemporal_load((const unsigned long long*)&P2[(size_t)i * 256 + 2 * cc]);
    float px = __uint_as_float((unsigned int)pv);
    float py = __uint_as_float((unsigned int)(pv >> 32));
    float h0 = sigm(px + z0);  // > 0 always
    float h1 = sigm(py + z1);
    int gb = bat[i] * 256 + 2 * cc;
    atomicMax((unsigned int*)&g[gb + 0], __float_as_uint(h0));
    atomicMax((unsigned int*)&g[gb + 1], __float_as_uint(h1));
}

// ---------------- head: out = sigmoid(g@W3+b3)@W4+b4 ----------------
__global__ void final_k(const float* __restrict__ g, const float* __restrict__ W3,
                        const float* __restrict__ b3, const float* __restrict__ W4,
                        const float* __restrict__ b4, float* __restrict__ out) {
    __shared__ float gs[256];
    __shared__ float ss[128];
    int b = blockIdx.x, t = threadIdx.x;  // 128 threads
    gs[t] = g[b * 256 + t];
    gs[t + 128] = g[b * 256 + 128 + t];
    __syncthreads();
    float acc = b3[t];
#pragma unroll 8
    for (int k = 0; k < 256; k++) acc += gs[k] * W3[k * 128 + t];
    ss[t] = sigm(acc);
    __syncthreads();
    if (t < 10) {
        float o = b4[t];
#pragma unroll 8
        for (int k = 0; k < 128; k++) o += ss[k] * W4[k * 10 + t];
        out[b * 10 + t] = o;
    }
}

extern "C" void kernel_launch(void* const* d_in, const int* in_sizes, int n_in,
                              void* d_out, int out_size, void* d_ws, size_t ws_size,
                              hipStream_t stream) {
    const float* x  = (const float*)d_in[0];
    const void*  ei_raw = d_in[1];
    const void*  b_raw  = d_in[2];
    const float* W1 = (const float*)d_in[3];
    const float* b1 = (const float*)d_in[4];
    const float* W2 = (const float*)d_in[5];
    const float* b2 = (const float*)d_in[6];
    const float* W3 = (const float*)d_in[7];
    const float* b3 = (const float*)d_in[8];
    const float* W4 = (const float*)d_in[9];
    const float* b4 = (const float*)d_in[10];

    char* ws = (char*)d_ws;
    size_t off = 0;
    auto alloc = [&](size_t bytes) {
        void* p = ws + off;
        off += (bytes + 255) & ~(size_t)255;
        return p;
    };
    int*            src    = (int*)alloc(N_EDGES * 4);
    int*            dst    = (int*)alloc(N_EDGES * 4);
    int*            bat    = (int*)alloc(N_NODES * 4);
    int*            deg    = (int*)alloc(N_NODES * 4);
    int*            offs   = (int*)alloc((N_NODES + 1) * 4);
    int*            cursor = (int*)alloc(N_NODES * 4);
    int*            csr    = (int*)alloc(N_EDGES * 4);
    float*          P1     = (float*)alloc((size_t)N_NODES * 128 * 4);
    unsigned short* Q1     = (unsigned short*)alloc((size_t)N_NODES * 128 * 2);
    unsigned short* h1h    = (unsigned short*)alloc((size_t)N_NODES * 128 * 2);
    unsigned short* h1l    = (unsigned short*)alloc((size_t)N_NODES * 128 * 2);
    unsigned short* Bh     = (unsigned short*)alloc(512 * 128 * 2);
    unsigned short* Bl     = (unsigned short*)alloc(512 * 128 * 2);
    float*          P2     = (float*)alloc((size_t)N_NODES * 256 * 4);
    unsigned short* Q2     = (unsigned short*)alloc((size_t)N_NODES * 256 * 2);
    float*          g      = (float*)alloc(N_GRAPHS * 256 * 4);

    hipMemsetAsync(deg, 0, N_NODES * 4, stream);

    prep_k<<<RB + RP + RW + 1, 256, 0, stream>>>(
        (const unsigned int*)ei_raw, (const unsigned int*)b_raw, x, W1, b1, W2,
        src, dst, bat, deg, P1, Q1, Bh, Bl, g);
    scan_k<<<1, 1024, 0, stream>>>(deg, offs, cursor, N_NODES);
    scatter_k<<<(N_EDGES + 255) / 256, 256, 0, stream>>>(src, dst, cursor, csr, N_EDGES);

    econv1_k<<<N_NODES, 64, 0, stream>>>(P1, (const unsigned int*)Q1, offs, csr, h1h, h1l);
    gemm2_k<<<dim3((N_NODES + 63) / 64, 8), 256, 0, stream>>>(h1h, h1l, Bh, Bl, b2, P2, Q2, N_NODES);

    econv2_k<<<dim3(N_NODES, 2), 64, 0, stream>>>(P2, (const unsigned int*)Q2, offs, csr, bat, g);
    final_k<<<N_GRAPHS, 128, 0, stream>>>(g, W3, b3, W4, b4, (float*)d_out);
}